// Round 1
// 180.733 us; speedup vs baseline: 1.0453x; 1.0453x over previous
//
#include <hip/hip_runtime.h>
#include <math.h>

#define HIDDEN 128
#define MAIN_BLOCKS 512
#define MAIN_THREADS 1024
#define MAX_BMAP_WORDS 6272   // 200704 bits >= 200000 nodes

// ---------------------------------------------------------------------------
// Fused kernel: every block (512 blocks x 1024 threads) redundantly computes
//   q  = [x ; X[start] ; X[prev]] @ Wq        (384x128 GEMV, split-K in LDS)
//   qk = (Wk @ q) / sqrt(128)                 (into LDS, no global round-trip)
// overlapped with its visited-bitmap build, then streams X with an online
// softmax + weighted sum (single pass, float4 per half-wave = 512B/row).
// Redundant Wq/Wk reads (512 x 260KB) are L2/L3 broadcasts — HBM sees them
// once; this removes the serial 1-block prep kernel + one dispatch boundary.
// ---------------------------------------------------------------------------
__global__ __launch_bounds__(MAIN_THREADS) void fused_kernel(
    const float* __restrict__ X, const float* __restrict__ x,
    const float* __restrict__ Wq, const float* __restrict__ Wk,
    const int* __restrict__ visited, int nv,
    const int* __restrict__ startp, const int* __restrict__ prevp,
    float* __restrict__ Mb, float* __restrict__ Sb, float* __restrict__ Gb,
    int n)
{
    __shared__ unsigned bmap[MAX_BMAP_WORDS];   // 25088 B
    __shared__ float fc[384];
    __shared__ float qpart[8][HIDDEN];          // 4 KB
    __shared__ float qv[HIDDEN];
    __shared__ float qks[HIDDEN];
    __shared__ float m_arr[32];
    __shared__ float s_arr[32];
    __shared__ float g_all[32 * HIDDEN];        // 16 KB
    // total ~47.3 KB -> 2 blocks/CU (wave-limited: 16 waves/block)

    const int tid  = threadIdx.x;
    const int lane = tid & 63;
    const int sub  = lane & 31;
    const int half = (lane >> 5) & 1;

    // ---- Phase 0: issue fc global loads early, zero bitmap meanwhile ----
    const int nwords = (n + 31) >> 5;
    float fcv = 0.f;
    if (tid < 384) {
        if (tid < 128)      fcv = x[tid];
        else if (tid < 256) fcv = X[(size_t)startp[0] * HIDDEN + (tid - 128)];
        else                fcv = X[(size_t)prevp[0]  * HIDDEN + (tid - 256)];
    }
    for (int w = tid; w < nwords; w += MAIN_THREADS) bmap[w] = 0u;
    if (tid < 384) fc[tid] = fcv;
    __syncthreads();

    // ---- Phase 1: visited scatter (dup-safe) + q partials (q = fc @ Wq) ----
    for (int i = tid; i < nv; i += MAIN_THREADS) {
        const int v = visited[i];
        atomicOr(&bmap[v >> 5], 1u << (v & 31));
    }
    {
        const int col = tid & (HIDDEN - 1);
        const int seg = tid >> 7;              // 0..7, 48 m-rows each
        const int m0  = seg * 48;
        float acc = 0.f;
        #pragma unroll 8
        for (int m = 0; m < 48; ++m)
            acc += fc[m0 + m] * Wq[(size_t)(m0 + m) * HIDDEN + col];
        qpart[seg][col] = acc;
    }
    __syncthreads();
    if (tid < HIDDEN)
        qv[tid] = ((qpart[0][tid] + qpart[1][tid]) + (qpart[2][tid] + qpart[3][tid]))
                + ((qpart[4][tid] + qpart[5][tid]) + (qpart[6][tid] + qpart[7][tid]));
    __syncthreads();

    // ---- Phase 2: qk rows; 32 half-waves x 4 rows, coalesced float4 ----
    {
        const int hw0 = tid >> 5;              // 0..31
        const float4 qv4 = *(const float4*)(&qv[sub << 2]);
        #pragma unroll
        for (int k = 0; k < 4; ++k) {
            const int row = hw0 + (k << 5);
            const float4 wk4 = *(const float4*)(Wk + (size_t)row * HIDDEN + (sub << 2));
            float p = wk4.x * qv4.x + wk4.y * qv4.y + wk4.z * qv4.z + wk4.w * qv4.w;
            #pragma unroll
            for (int off = 16; off >= 1; off >>= 1)
                p += __shfl_xor(p, off, 64);   // off<=16 stays within 32-lane half
            if (sub == 0) qks[row] = p * 0.08838834764831845f;
        }
    }
    __syncthreads();

    // ---- Phase 3: streaming online softmax + weighted sum over X ----
    const int wavesPerBlock = MAIN_THREADS >> 6;          // 16
    const int gw  = blockIdx.x * wavesPerBlock + (tid >> 6);
    const int vhw = gw * 2 + half;
    const int T   = gridDim.x * wavesPerBlock * 2;        // 16384 half-waves

    const float4 qkv = *(const float4*)(&qks[sub << 2]);

    float m = -INFINITY, s = 0.f;
    float g0 = 0.f, g1 = 0.f, g2 = 0.f, g3 = 0.f;

    for (int r = vhw; r < n; r += T) {
        const float4 xv = *(const float4*)(X + (size_t)r * HIDDEN + (sub << 2));
        float p = xv.x * qkv.x + xv.y * qkv.y + xv.z * qkv.z + xv.w * qkv.w;
        #pragma unroll
        for (int off = 16; off >= 1; off >>= 1)
            p += __shfl_xor(p, off, 64);
        const float maskv = ((bmap[r >> 5] >> (r & 31)) & 1u) ? 0.f : 1.f;
        const float u  = p + maskv;
        const float mn    = fmaxf(m, u);
        const float scale = __expf(m - mn);   // exp(-inf)=0 on first iter
        const float w     = __expf(u - mn);
        s  = s  * scale + w;
        g0 = g0 * scale + w * xv.x;
        g1 = g1 * scale + w * xv.y;
        g2 = g2 * scale + w * xv.z;
        g3 = g3 * scale + w * xv.w;
        m  = mn;
    }

    // ---- block combine: 32 half-waves -> 1 partial ----
    const int hw = tid >> 5;
    *(float4*)(&g_all[hw * HIDDEN + (sub << 2)]) = make_float4(g0, g1, g2, g3);
    if (sub == 0) { m_arr[hw] = m; s_arr[hw] = s; }
    __syncthreads();

    float mb = m_arr[0];
    #pragma unroll
    for (int h = 1; h < 32; ++h) mb = fmaxf(mb, m_arr[h]);

    if (tid < HIDDEN) {
        float G = 0.f;
        #pragma unroll 4
        for (int h = 0; h < 32; ++h)
            G += g_all[h * HIDDEN + tid] * __expf(m_arr[h] - mb);
        Gb[blockIdx.x * HIDDEN + tid] = G;
    } else if (tid == HIDDEN) {
        float S = 0.f;
        #pragma unroll
        for (int h = 0; h < 32; ++h) S += s_arr[h] * __expf(m_arr[h] - mb);
        Sb[blockIdx.x] = S;
        Mb[blockIdx.x] = mb;
    }
}

// ---------------------------------------------------------------------------
// Finish: merge block partials -> pvec = softmax-weighted mean of X rows,
// then h = pvec@Wv, out = h@Wo. One block, 512 threads. Kernel boundary
// provides cross-XCD visibility of Mb/Sb/Gb (no fence games needed).
// ---------------------------------------------------------------------------
__global__ __launch_bounds__(512) void finish_kernel(
    const float* __restrict__ Mb, const float* __restrict__ Sb,
    const float* __restrict__ Gb,
    const float* __restrict__ Wv, const float* __restrict__ Wo,
    float* __restrict__ out, int B)
{
    __shared__ float red[512];
    __shared__ float e[MAIN_BLOCKS];
    __shared__ float part[4][HIDDEN];
    __shared__ float pvec[HIDDEN];
    __shared__ float hvec[HIDDEN];
    const int t   = threadIdx.x;
    const int col = t & (HIDDEN - 1);
    const int seg = t >> 7;               // 0..3

    // global max over B=512 block maxima (one per thread)
    const float mt = (t < B) ? Mb[t] : -INFINITY;
    red[t] = mt; __syncthreads();
    for (int st = 256; st >= 1; st >>= 1) {
        if (t < st) red[t] = fmaxf(red[t], red[t + st]);
        __syncthreads();
    }
    const float M = red[0];
    __syncthreads();

    // per-block scale + global softmax denominator
    float ls = 0.f;
    if (t < B) { const float eb = __expf(mt - M); e[t] = eb; ls = Sb[t] * eb; }
    red[t] = ls; __syncthreads();
    for (int st = 256; st >= 1; st >>= 1) {
        if (t < st) red[t] += red[t + st];
        __syncthreads();
    }
    const float S = red[0];
    __syncthreads();

    // G[col] = sum_b Gb[b,col]*e[b]; split b into 4 segments of B/4
    {
        float acc = 0.f;
        const int b0 = seg * (B >> 2);
        #pragma unroll 8
        for (int b = 0; b < (MAIN_BLOCKS >> 2); ++b)
            acc += Gb[(size_t)(b0 + b) * HIDDEN + col] * e[b0 + b];
        part[seg][col] = acc;
    }
    __syncthreads();
    if (t < HIDDEN)
        pvec[t] = (part[0][t] + part[1][t] + part[2][t] + part[3][t]) / S;
    __syncthreads();

    // h[col] = sum_m pvec[m]*Wv[m,col]; split m into 4 segments of 32
    {
        float acc = 0.f;
        const int m0 = seg * 32;
        #pragma unroll 8
        for (int m = 0; m < 32; ++m)
            acc += pvec[m0 + m] * Wv[(size_t)(m0 + m) * HIDDEN + col];
        part[seg][col] = acc;
    }
    __syncthreads();
    if (t < HIDDEN)
        hvec[t] = part[0][t] + part[1][t] + part[2][t] + part[3][t];
    __syncthreads();

    // out[col] = sum_m h[m]*Wo[m,col]
    {
        float acc = 0.f;
        const int m0 = seg * 32;
        #pragma unroll 8
        for (int m = 0; m < 32; ++m)
            acc += hvec[m0 + m] * Wo[(size_t)(m0 + m) * HIDDEN + col];
        part[seg][col] = acc;
    }
    __syncthreads();
    if (t < HIDDEN)
        out[t] = part[0][t] + part[1][t] + part[2][t] + part[3][t];
}

// ---------------------------------------------------------------------------
extern "C" void kernel_launch(void* const* d_in, const int* in_sizes, int n_in,
                              void* d_out, int out_size, void* d_ws, size_t ws_size,
                              hipStream_t stream)
{
    const float* X       = (const float*)d_in[0];
    const float* x       = (const float*)d_in[1];
    const float* Wq      = (const float*)d_in[2];
    const float* Wk      = (const float*)d_in[3];
    const float* Wv      = (const float*)d_in[4];
    const float* Wo      = (const float*)d_in[5];
    const int*   visited = (const int*)d_in[6];
    const int*   startp  = (const int*)d_in[7];
    const int*   prevp   = (const int*)d_in[8];

    const int n  = in_sizes[0] / HIDDEN;   // 200000
    const int nv = in_sizes[6];            // 1024

    float* ws = (float*)d_ws;
    float* Mb = ws + 128;                  // keep prior layout (slot 0 unused)
    float* Sb = Mb + MAIN_BLOCKS;
    float* Gb = Sb + MAIN_BLOCKS;          // MAIN_BLOCKS*128

    fused_kernel<<<MAIN_BLOCKS, MAIN_THREADS, 0, stream>>>(
        X, x, Wq, Wk, visited, nv, startp, prevp, Mb, Sb, Gb, n);
    finish_kernel<<<1, 512, 0, stream>>>(Mb, Sb, Gb, Wv, Wo, (float*)d_out, MAIN_BLOCKS);
}